// Round 1
// baseline (253.972 us; speedup 1.0000x reference)
//
#include <hip/hip_runtime.h>
#include <stdint.h>

typedef short bf16x8 __attribute__((ext_vector_type(8)));
typedef float f32x4 __attribute__((ext_vector_type(4)));
typedef unsigned short ushort_t;
typedef ushort_t ushort8 __attribute__((ext_vector_type(8)));

#define TOKENS 131072
#define DMODEL 128
#define DIN 160
#define DHID 512
#define NEXP 8
#define BEH 32
#define CAP 24576
#define MT 128
#define TILES 192  /* CAP / MT */

// workspace layout (bytes)
#define OFF_COUNTS 0
#define OFF_LISTS  1024
#define OFF_WIP    (OFF_LISTS + NEXP*CAP*4)          /* 787456, 16B aligned */
#define OFF_WOP    (OFF_WIP + 8*32*5*64*8*2)         /* + 1310720 */
/* total ~3.15 MB */

__device__ __forceinline__ ushort_t f2b(float f) {
    union { float f; uint32_t u; } x; x.f = f;
    uint32_t r = x.u + 0x7FFF + ((x.u >> 16) & 1);   // RNE
    return (ushort_t)(r >> 16);
}

// ---------------- Phase A: bucket tokens by expert ----------------
__global__ __launch_bounds__(256) void scatter_kernel(
    const int* __restrict__ pos, int* __restrict__ counts, int* __restrict__ lists)
{
    __shared__ int lcnt[NEXP];
    __shared__ int lbase[NEXP];
    int tid = threadIdx.x;
    if (tid < NEXP) lcnt[tid] = 0;
    __syncthreads();
    int t = blockIdx.x * 256 + tid;           // grid exactly covers TOKENS
    int e = pos[t];
    int slot = atomicAdd(&lcnt[e], 1);
    __syncthreads();
    if (tid < NEXP) lbase[tid] = atomicAdd(&counts[tid], lcnt[tid]);
    __syncthreads();
    int p = lbase[e] + slot;
    if (p < CAP) lists[e * CAP + p] = t;
}

// ---------------- Phase B: pack weights to bf16 MFMA-B-fragment layout ----------------
// B-frag for 16x16x32: lane L holds B[k = (L>>4)*8 + j][n = L&15], j=0..7
// wiP index: (((e*32 + t1)*5 + s)*64 + L)*8 + j ; k = s*32+(L>>4)*8+j ; n = t1*16+(L&15)
// woP index: (((e*8 + t2)*16 + ks)*64 + L)*8 + j ; k = ks*32+(L>>4)*8+j ; n = t2*16+(L&15)
__global__ __launch_bounds__(256) void pack_weights(
    const float* __restrict__ Wi, const float* __restrict__ Wo,
    ushort_t* __restrict__ wiP, ushort_t* __restrict__ woP)
{
    int idx = blockIdx.x * 256 + threadIdx.x;
    const int NWI = 8 * 32 * 5 * 64;   // 81920
    if (idx < NWI) {
        int L = idx & 63; int r = idx >> 6;
        int s = r % 5; r /= 5;
        int t1 = r & 31; int e = r >> 5;
        int n = t1 * 16 + (L & 15);
        int kb = s * 32 + ((L >> 4) & 3) * 8;
        ushort8 o;
        #pragma unroll
        for (int j = 0; j < 8; ++j)
            o[j] = f2b(Wi[((size_t)e * DIN + kb + j) * DHID + n]);
        *(ushort8*)(wiP + (size_t)idx * 8) = o;
    } else {
        int i2 = idx - NWI;
        if (i2 >= 8 * 8 * 16 * 64) return;   // 65536
        int L = i2 & 63; int r = i2 >> 6;
        int ks = r & 15; r >>= 4;
        int t2 = r & 7; int e = r >> 3;
        int n = t2 * 16 + (L & 15);
        int kb = ks * 32 + ((L >> 4) & 3) * 8;
        ushort8 o;
        #pragma unroll
        for (int j = 0; j < 8; ++j)
            o[j] = f2b(Wo[((size_t)e * DHID + kb + j) * DMODEL + n]);
        *(ushort8*)(woP + (size_t)i2 * 8) = o;
    }
}

// ---------------- Phase C: per-expert fused MLP GEMM ----------------
// block: 128 tokens of one expert; 4 waves; y = relu(x @ Wi[e]) @ Wo[e]
__global__ __launch_bounds__(256, 2) void expert_gemm(
    const float* __restrict__ hidden, const int* __restrict__ bindex,
    const int* __restrict__ lists, const int* __restrict__ counts,
    const ushort_t* __restrict__ wiP, const ushort_t* __restrict__ woP,
    const float* __restrict__ emb, float* __restrict__ out)
{
    int e = blockIdx.y;
    int tile = blockIdx.x;
    int count = counts[e]; if (count > CAP) count = CAP;
    int base = tile * MT;
    if (base >= count) return;                 // uniform exit, before barriers
    int mvalid = count - base; if (mvalid > MT) mvalid = MT;

    __shared__ int tokLds[MT];
    __shared__ int bidLds[MT];
    __shared__ ushort_t xLds[MT * 160];        // [row][20 granules of 8 bf16], xor-swizzled
    __shared__ ushort_t hLds[MT * 64];         // [row][8 granules], xor-swizzled, per-wave-private rows

    int tid = threadIdx.x;
    if (tid < MT) {
        int t = -1, bi = 0;
        if (tid < mvalid) { t = lists[e * CAP + base + tid]; bi = bindex[t]; }
        tokLds[tid] = t; bidLds[tid] = bi;
    }
    __syncthreads();

    // stage x = concat(hidden[t], emb[bi]) as bf16, swizzled: pg = g ^ ((r>>1)&3)
    for (int idx = tid; idx < MT * 20; idx += 256) {
        int r = idx / 20, g = idx - r * 20;
        ushort8 o;
        int t = tokLds[r];
        if (t >= 0) {
            int c0 = g * 8;
            const float* src = (c0 < DMODEL)
                ? (hidden + (size_t)t * DMODEL + c0)
                : (emb + (size_t)bidLds[r] * BEH + (c0 - DMODEL));
            f32x4 p0 = *(const f32x4*)src;
            f32x4 p1 = *(const f32x4*)(src + 4);
            o[0]=f2b(p0[0]); o[1]=f2b(p0[1]); o[2]=f2b(p0[2]); o[3]=f2b(p0[3]);
            o[4]=f2b(p1[0]); o[5]=f2b(p1[1]); o[6]=f2b(p1[2]); o[7]=f2b(p1[3]);
        } else {
            o = (ushort8)0;
        }
        int pg = g ^ ((r >> 1) & 3);
        *(ushort8*)&xLds[r * 160 + pg * 8] = o;
    }
    __syncthreads();

    int lane = tid & 63;
    int w = tid >> 6;
    int l15 = lane & 15;
    int quad = lane >> 4;
    int rowA0 = w * 32 + l15;
    int rowA1 = rowA0 + 16;

    f32x4 yacc[2][8] = {};

    #pragma unroll 1
    for (int c = 0; c < 8; ++c) {              // 8 chunks of 64 hidden units
        f32x4 hacc[2][4] = {};
        // GEMM1: h[128 x 64] = x[128 x 160] @ Wi_chunk
        #pragma unroll
        for (int s = 0; s < 5; ++s) {
            int g = s * 4 + quad;
            bf16x8 a0 = *(const bf16x8*)&xLds[rowA0 * 160 + (g ^ ((rowA0 >> 1) & 3)) * 8];
            bf16x8 a1 = *(const bf16x8*)&xLds[rowA1 * 160 + (g ^ ((rowA1 >> 1) & 3)) * 8];
            #pragma unroll
            for (int nt = 0; nt < 4; ++nt) {
                bf16x8 b = *(const bf16x8*)(wiP +
                    ((size_t)(((e * 32 + (c * 4 + nt)) * 5 + s) * 64 + lane)) * 8);
                hacc[0][nt] = __builtin_amdgcn_mfma_f32_16x16x32_bf16(a0, b, hacc[0][nt], 0, 0, 0);
                hacc[1][nt] = __builtin_amdgcn_mfma_f32_16x16x32_bf16(a1, b, hacc[1][nt], 0, 0, 0);
            }
        }
        // relu + store h to LDS (C-layout -> A-layout round trip; rows are wave-private)
        #pragma unroll
        for (int mt = 0; mt < 2; ++mt)
            #pragma unroll
            for (int nt = 0; nt < 4; ++nt)
                #pragma unroll
                for (int r = 0; r < 4; ++r) {
                    int row = w * 32 + mt * 16 + quad * 4 + r;
                    int col = nt * 16 + l15;
                    float v = hacc[mt][nt][r]; v = v > 0.f ? v : 0.f;
                    int pg = (col >> 3) ^ (row & 7);
                    hLds[row * 64 + pg * 8 + (col & 7)] = f2b(v);
                }
        // GEMM2: y += relu(h)[128 x 64] @ Wo_chunk   (no barrier: per-wave rows)
        #pragma unroll
        for (int s2 = 0; s2 < 2; ++s2) {
            int g = s2 * 4 + quad;
            bf16x8 a0 = *(const bf16x8*)&hLds[rowA0 * 64 + (g ^ (rowA0 & 7)) * 8];
            bf16x8 a1 = *(const bf16x8*)&hLds[rowA1 * 64 + (g ^ (rowA1 & 7)) * 8];
            int ks = c * 2 + s2;
            #pragma unroll
            for (int t2 = 0; t2 < 8; ++t2) {
                bf16x8 b = *(const bf16x8*)(woP +
                    ((size_t)(((e * 8 + t2) * 16 + ks) * 64 + lane)) * 8);
                yacc[0][t2] = __builtin_amdgcn_mfma_f32_16x16x32_bf16(a0, b, yacc[0][t2], 0, 0, 0);
                yacc[1][t2] = __builtin_amdgcn_mfma_f32_16x16x32_bf16(a1, b, yacc[1][t2], 0, 0, 0);
            }
        }
    }

    // epilogue: C-layout scatter to out[token][dmodel]
    #pragma unroll
    for (int mt = 0; mt < 2; ++mt)
        #pragma unroll
        for (int r = 0; r < 4; ++r) {
            int row = w * 32 + mt * 16 + quad * 4 + r;
            if (row < mvalid) {
                int t = tokLds[row];
                float* dst = out + (size_t)t * DMODEL + l15;
                #pragma unroll
                for (int t2 = 0; t2 < 8; ++t2)
                    dst[t2 * 16] = yacc[mt][t2][r];
            }
        }
}

extern "C" void kernel_launch(void* const* d_in, const int* in_sizes, int n_in,
                              void* d_out, int out_size, void* d_ws, size_t ws_size,
                              hipStream_t stream) {
    const float* hidden = (const float*)d_in[0];
    const int*   pos    = (const int*)d_in[1];
    const int*   beh    = (const int*)d_in[2];
    const float* Wi     = (const float*)d_in[3];
    const float* Wo     = (const float*)d_in[4];
    const float* emb    = (const float*)d_in[5];

    char* ws = (char*)d_ws;
    int* counts   = (int*)(ws + OFF_COUNTS);
    int* lists    = (int*)(ws + OFF_LISTS);
    ushort_t* wiP = (ushort_t*)(ws + OFF_WIP);
    ushort_t* woP = (ushort_t*)(ws + OFF_WOP);

    hipMemsetAsync(counts, 0, NEXP * sizeof(int), stream);
    scatter_kernel<<<TOKENS / 256, 256, 0, stream>>>(pos, counts, lists);
    pack_weights<<<(8*32*5*64 + 8*8*16*64 + 255) / 256, 256, 0, stream>>>(Wi, Wo, wiP, woP);
    expert_gemm<<<dim3(TILES, NEXP), 256, 0, stream>>>(
        hidden, beh, lists, counts, wiP, woP, emb, (float*)d_out);
}